// Round 3
// baseline (1379.957 us; speedup 1.0000x reference)
//
#include <hip/hip_runtime.h>
#include <math.h>

#define B 4
#define T1 16
#define T2 16
#define SEG 4
#define V 8000
#define E 256
#define H 256
#define ENC 512
#define EOS 2
#define NEGV -1e30f
#define G4 1024
#define NCELL 1088
#define NBV 125
#define T21 17

typedef __attribute__((ext_vector_type(4))) float f32x4;
typedef __attribute__((ext_vector_type(8))) short bf16x8;

__device__ __forceinline__ float sigm(float x) { return 1.f / (1.f + __expf(-x)); }
__device__ __forceinline__ float b2f(short x) {
    unsigned u = ((unsigned)(unsigned short)x) << 16;
    return __builtin_bit_cast(float, u);
}
__device__ __forceinline__ short f2b(float f) {
    unsigned u = __builtin_bit_cast(unsigned, f);
    unsigned r = (u + 0x7fffu + ((u >> 16) & 1u)) >> 16;
    return (short)r;
}

// ---------------- fused setup: casts / transposes / gate-interleave permutes ----------------
// block ranges: [0,8000) fcw cast; [8000,9024) whh0i; [9024,11072) w1i; [11072,11584) projhT;
// [11584,12096) projcT; [12096,14144) split wih0; [14144,14148) b1i
__global__ void k_setup(const float* __restrict__ fcw, const float* __restrict__ whh0,
                        const float* __restrict__ wih1, const float* __restrict__ whh1,
                        const float* __restrict__ phw, const float* __restrict__ pcw,
                        const float* __restrict__ wih0, const float* __restrict__ b1,
                        short* __restrict__ fcwbf, short* __restrict__ whh0i, short* __restrict__ w1i,
                        float* __restrict__ projhT, float* __restrict__ projcT,
                        float* __restrict__ ctxT, float* __restrict__ xT, float* __restrict__ b1i) {
    int bid = blockIdx.x, tid = threadIdx.x;
    if (bid < 8000) { int i = bid * 256 + tid; fcwbf[i] = f2b(fcw[i]); return; }
    bid -= 8000;
    if (bid < 1024) {
        int i = bid * 256 + tid; int gp = i >> 8, k = i & 255; int j = gp >> 2, gate = gp & 3;
        whh0i[i] = f2b(whh0[(size_t)(gate * 256 + j) * 256 + k]); return;
    }
    bid -= 1024;
    if (bid < 2048) {
        int i = bid * 256 + tid; int gp = i >> 9, k = i & 511; int j = gp >> 2, gate = gp & 3;
        float v = (k < 256) ? wih1[(size_t)(gate * 256 + j) * 256 + k]
                            : whh1[(size_t)(gate * 256 + j) * 256 + (k - 256)];
        w1i[i] = f2b(v); return;
    }
    bid -= 2048;
    if (bid < 512) { int i = bid * 256 + tid; int k = i >> 8, r = i & 255; projhT[i] = phw[(size_t)r * ENC + k]; return; }
    bid -= 512;
    if (bid < 512) { int i = bid * 256 + tid; int k = i >> 8, r = i & 255; projcT[i] = pcw[(size_t)r * ENC + k]; return; }
    bid -= 512;
    if (bid < 2048) {
        int i = bid * 256 + tid; int g = i >> 9, k = i & 511; float v = wih0[i];
        if (k < 256) ctxT[(size_t)k * G4 + g] = v; else xT[(size_t)(k - 256) * G4 + g] = v;
        return;
    }
    bid -= 2048;
    if (bid < 4) { int i = bid * 256 + tid; int j = i >> 2, gate = i & 3; b1i[i] = b1[gate * 256 + j]; return; }
}

// ---------------- h0/c0 = eo @ projT + b ----------------
__global__ void k_init_state(const float* __restrict__ enc, const float* __restrict__ phT,
                             const float* __restrict__ phb, const float* __restrict__ pcT,
                             const float* __restrict__ pcb, float* __restrict__ h0, float* __restrict__ c0) {
    __shared__ float eo[ENC];
    int bi = blockIdx.x;
    int b = bi / T1, i = bi % T1;
    int j = threadIdx.x;
    for (int e = j; e < ENC; e += 256) eo[e] = enc[(size_t)(i * B + b) * ENC + e];
    __syncthreads();
    float ha = phb[j], ca = pcb[j];
    for (int e = 0; e < ENC; ++e) {
        float x = eo[e];
        ha += x * phT[(size_t)e * H + j];
        ca += x * pcT[(size_t)e * H + j];
    }
    h0[(size_t)bi * H + j] = ha;
    c0[(size_t)bi * H + j] = ca;
}

// ---------------- fused init: state broadcast + pre_ctx (interleaved) + pre_x (interleaved) ----------------
// blocks: [0,1088) bcast; [1088,1152) prectx; [1152,1492) prex
__global__ void k_init2(const int* __restrict__ y, const float* __restrict__ embed, const float* __restrict__ se,
                        const float* __restrict__ h0, const float* __restrict__ c0,
                        const float* __restrict__ ctxT, const float* __restrict__ xT,
                        const float* __restrict__ b0,
                        float* __restrict__ c1, float* __restrict__ c2,
                        short* __restrict__ hc0, short* __restrict__ h2buf,
                        float* __restrict__ pre_ctxi, float* __restrict__ pre_xi) {
    __shared__ float sb[256];
    int bid = blockIdx.x, j = threadIdx.x;
    if (bid < NCELL) {
        int cell = bid, bi = cell / T21;
        c1[(size_t)cell * H + j] = c0[(size_t)bi * H + j];
        c2[(size_t)cell * H + j] = 0.f;
        hc0[(size_t)cell * 512 + j] = f2b(h0[(size_t)bi * H + j]);
        h2buf[(size_t)cell * H + j] = 0;
        return;
    }
    bid -= NCELL;
    if (bid < 64) {
        int bi = bid;
        sb[j] = h0[(size_t)bi * H + j];
        __syncthreads();
        float a0 = b0[j], a1 = b0[256 + j], a2 = b0[512 + j], a3 = b0[768 + j];
        for (int k = 0; k < H; ++k) {
            float x = sb[k];
            const float* w = ctxT + (size_t)k * G4;
            a0 += x * w[j]; a1 += x * w[256 + j]; a2 += x * w[512 + j]; a3 += x * w[768 + j];
        }
        *(float4*)&pre_ctxi[(size_t)bi * G4 + 4 * j] = make_float4(a0, a1, a2, a3);
        return;
    }
    bid -= 64;
    int row = bid;                    // (s*B + b)*T21 + t
    int s = row / (B * T21), rem = row % (B * T21);
    int b = rem / T21, t = rem % T21;
    const float* src;
    if (s == 0) src = se;
    else { int tt = t + s - 1; if (tt > 15) tt = 15; src = embed + (size_t)y[b * T2 + tt] * E; }
    sb[j] = src[j];
    __syncthreads();
    float a0 = 0, a1 = 0, a2 = 0, a3 = 0;
    for (int k = 0; k < E; ++k) {
        float x = sb[k];
        const float* w = xT + (size_t)k * G4;
        a0 += x * w[j]; a1 += x * w[256 + j]; a2 += x * w[512 + j]; a3 += x * w[768 + j];
    }
    *(float4*)&pre_xi[(size_t)row * G4 + 4 * j] = make_float4(a0, a1, a2, a3);
}

// ---------------- fused LSTM layer: MFMA GEMM (interleaved gates) + nonlinearity ----------------
// grid (NCELL/64, G4/64=16), block 256 (4 waves). A rows stride 512.
// LAYER 0: A = IN cols[0,256) (h1_prev); out: OUT[j]=h1_new, OUT[256+j]=h2buf[j] (copy h2_prev)
// LAYER 1: A = OUT cols[0,512) ([h1_new|h2_prev]); out: h2buf[j]=h2_new
template<int LAYER>
__global__ void k_lstm(int s, const short* __restrict__ A, const short* __restrict__ Bw,
                       const float* __restrict__ pre_ctxi, const float* __restrict__ pre_xi,
                       const float* __restrict__ b1i, float* __restrict__ cst,
                       short* __restrict__ OUT, short* __restrict__ h2buf) {
    constexpr int K = LAYER ? 512 : 256;
    __shared__ float sg[64][68];
    int tid = threadIdx.x;
    int wave = tid >> 6, lane = tid & 63, ln = lane & 15, kg = lane >> 4;
    int m0 = blockIdx.x * 64 + wave * 16;
    int n0 = blockIdx.y * 64;
    const short* Ap = A + (size_t)(m0 + ln) * 512 + kg * 8;
    const short* Bp = Bw + (size_t)(n0 + ln) * K + kg * 8;
    f32x4 acc[4] = {};
#pragma unroll
    for (int k = 0; k < K; k += 32) {
        bf16x8 a = *(const bf16x8*)(Ap + k);
#pragma unroll
        for (int nf = 0; nf < 4; ++nf) {
            bf16x8 b = *(const bf16x8*)(Bp + (size_t)nf * 16 * K + k);
            acc[nf] = __builtin_amdgcn_mfma_f32_16x16x32_bf16(a, b, acc[nf], 0, 0, 0);
        }
    }
#pragma unroll
    for (int nf = 0; nf < 4; ++nf)
#pragma unroll
        for (int r = 0; r < 4; ++r)
            sg[wave * 16 + kg * 4 + r][nf * 16 + ln] = acc[nf][r];
    __syncthreads();
    int jlo = n0 >> 2;
#pragma unroll
    for (int q = 0; q < 4; ++q) {
        int item = q * 256 + tid;
        int c = item >> 4, jj = item & 15;
        int cell = blockIdx.x * 64 + c;
        int j = jlo + jj;
        float4 g = *(float4*)&sg[c][4 * jj];
        float ig, fg, gg, og;
        if constexpr (LAYER == 0) {
            int bi = cell / T21;
            int b = bi >> 4;
            int t = cell % T21;
            int prow = (s * B + b) * T21 + t;
            float4 pc = *(const float4*)&pre_ctxi[(size_t)bi * G4 + 4 * j];
            float4 px = *(const float4*)&pre_xi[(size_t)prow * G4 + 4 * j];
            ig = g.x + pc.x + px.x; fg = g.y + pc.y + px.y;
            gg = g.z + pc.z + px.z; og = g.w + pc.w + px.w;
        } else {
            float4 bb = *(const float4*)&b1i[4 * j];
            ig = g.x + bb.x; fg = g.y + bb.y; gg = g.z + bb.z; og = g.w + bb.w;
        }
        float cold = cst[(size_t)cell * H + j];
        float cn = sigm(fg) * cold + sigm(ig) * tanhf(gg);
        float hn = sigm(og) * tanhf(cn);
        cst[(size_t)cell * H + j] = cn;
        if constexpr (LAYER == 0) {
            OUT[(size_t)cell * 512 + j] = f2b(hn);
            OUT[(size_t)cell * 512 + 256 + j] = h2buf[(size_t)cell * H + j];
        } else {
            h2buf[(size_t)cell * H + j] = f2b(hn);
        }
    }
}

// ---------------- fc GEMM + fused LSE partials + last-block combine + tgt/EOS dots ----------------
// grid (17, 125), block 256; A = h2buf [NCELL][256] bf16
__global__ void k_fc_score(int s, const short* __restrict__ h2buf, const short* __restrict__ Wv,
                           const float* __restrict__ fcb, const int* __restrict__ y,
                           float* __restrict__ pm, float* __restrict__ ps,
                           float* __restrict__ sel, float* __restrict__ eosp,
                           int* __restrict__ cnt) {
    __shared__ int win;
    int tid = threadIdx.x;
    int wave = tid >> 6, lane = tid & 63, ln = lane & 15, kg = lane >> 4;
    int m0 = blockIdx.x * 64 + wave * 16;
    int n0 = blockIdx.y * 64;
    const short* Ap = h2buf + (size_t)(m0 + ln) * 256 + kg * 8;
    const short* Bp = Wv + (size_t)(n0 + ln) * 256 + kg * 8;
    f32x4 acc[4] = {};
#pragma unroll
    for (int k = 0; k < 256; k += 32) {
        bf16x8 a = *(const bf16x8*)(Ap + k);
#pragma unroll
        for (int nf = 0; nf < 4; ++nf) {
            bf16x8 b = *(const bf16x8*)(Bp + (size_t)nf * 16 * 256 + k);
            acc[nf] = __builtin_amdgcn_mfma_f32_16x16x32_bf16(a, b, acc[nf], 0, 0, 0);
        }
    }
    float m_[4], s_[4];
#pragma unroll
    for (int r = 0; r < 4; ++r) { m_[r] = -3.4e38f; s_[r] = 0.f; }
#pragma unroll
    for (int nf = 0; nf < 4; ++nf) {
        float fb = fcb[n0 + nf * 16 + ln];
#pragma unroll
        for (int r = 0; r < 4; ++r) {
            float v = acc[nf][r] + fb;
            float M = fmaxf(m_[r], v);
            s_[r] = s_[r] * __expf(m_[r] - M) + __expf(v - M);
            m_[r] = M;
        }
    }
#pragma unroll
    for (int mask = 1; mask < 16; mask <<= 1) {
#pragma unroll
        for (int r = 0; r < 4; ++r) {
            float om = __shfl_xor(m_[r], mask);
            float os = __shfl_xor(s_[r], mask);
            float M = fmaxf(m_[r], om);
            s_[r] = s_[r] * __expf(m_[r] - M) + os * __expf(om - M);
            m_[r] = M;
        }
    }
    if (ln == 0) {
#pragma unroll
        for (int r = 0; r < 4; ++r) {
            int cell = m0 + kg * 4 + r;
            pm[(size_t)blockIdx.y * NCELL + cell] = m_[r];
            ps[(size_t)blockIdx.y * NCELL + cell] = s_[r];
        }
    }
    __threadfence();
    __syncthreads();
    if (tid == 0) { int old = atomicAdd(cnt + blockIdx.x, 1); win = (old == NBV - 1); }
    __syncthreads();
    if (!win) return;
    __threadfence();
    // phase 2 (one winner block per mblock): tgt/EOS dots + 125-partial LSE combine
    int cl = tid >> 2, q = tid & 3;
    int cell = blockIdx.x * 64 + cl;
    int b = cell / (T1 * T21);
    int t = cell % T21;
    int tv = 0;
    if (s < SEG) { int tt = t + s; if (tt > 15) tt = 15; tv = y[b * T2 + tt]; }
    const short* hp = h2buf + (size_t)cell * 256 + q * 64;
    const short* w1 = Wv + (size_t)tv * 256 + q * 64;
    const short* w2 = Wv + (size_t)EOS * 256 + q * 64;
    float d1 = 0.f, d2 = 0.f;
#pragma unroll
    for (int u = 0; u < 8; ++u) {
        bf16x8 av  = *(const bf16x8*)(hp + u * 8);
        bf16x8 wv1 = *(const bf16x8*)(w1 + u * 8);
        bf16x8 wv2 = *(const bf16x8*)(w2 + u * 8);
#pragma unroll
        for (int e = 0; e < 8; ++e) {
            float a = b2f(av[e]);
            d1 += a * b2f(wv1[e]);
            d2 += a * b2f(wv2[e]);
        }
    }
    d1 += __shfl_xor(d1, 1); d1 += __shfl_xor(d1, 2);
    d2 += __shfl_xor(d2, 1); d2 += __shfl_xor(d2, 2);
    float mm = -3.4e38f, ss = 0.f;
    for (int v2 = q * 32; v2 < q * 32 + 32 && v2 < NBV; ++v2) {
        float om = pm[(size_t)v2 * NCELL + cell], os = ps[(size_t)v2 * NCELL + cell];
        float M = fmaxf(mm, om);
        ss = ss * __expf(mm - M) + os * __expf(om - M);
        mm = M;
    }
#pragma unroll
    for (int d = 1; d < 4; d <<= 1) {
        float om = __shfl_xor(mm, d), os = __shfl_xor(ss, d);
        float M = fmaxf(mm, om);
        ss = ss * __expf(mm - M) + os * __expf(om - M);
        mm = M;
    }
    if (q == 0) {
        float lse = mm + __logf(ss);
        sel[s * NCELL + cell]  = d1 + fcb[tv]  - lse;
        eosp[s * NCELL + cell] = d2 + fcb[EOS] - lse;
    }
}

// ---------------- final DP, fully LDS-resident ----------------
__global__ void k_dp(const float* __restrict__ sel, const float* __restrict__ eosp, float* __restrict__ out) {
    __shared__ float row[SEG + 1][NCELL];
    __shared__ float alpha[B][T21];
    int tid = threadIdx.x;
    for (int c = tid; c < NCELL; c += 256) {
        float cum = 0.f;
        row[0][c] = eosp[c];
#pragma unroll
        for (int j = 1; j <= SEG; ++j) {
            cum += sel[(j - 1) * NCELL + c];
            row[j][c] = cum + eosp[j * NCELL + c];
        }
    }
    int b = tid / T21, t = tid % T21;
    bool act = tid < B * T21;
    if (act) alpha[b][t] = (t == 0) ? 0.f : NEGV;
    __syncthreads();
    for (int i = 0; i < T1; ++i) {
        float val = NEGV;
        if (act) {
            float terms[SEG + 1];
            float mx = -3.4e38f;
            int cnt2 = 0;
            for (int j = 0; j <= SEG && j <= t; ++j) {
                int cell = (b * T1 + i) * T21 + (t - j);
                float term = alpha[b][t - j] + row[j][cell];
                terms[cnt2++] = term;
                mx = fmaxf(mx, term);
            }
            float ssum = 0.f;
            for (int k2 = 0; k2 < cnt2; ++k2) ssum += __expf(terms[k2] - mx);
            val = mx + __logf(ssum);
        }
        __syncthreads();
        if (act) alpha[b][t] = val;
        __syncthreads();
    }
    if (act && t == T2) out[b] = alpha[b][T2];
}

extern "C" void kernel_launch(void* const* d_in, const int* in_sizes, int n_in,
                              void* d_out, int out_size, void* d_ws, size_t ws_size,
                              hipStream_t stream) {
    const int*   y     = (const int*)d_in[0];
    const float* enc   = (const float*)d_in[1];
    const float* embed = (const float*)d_in[2];
    const float* se    = (const float*)d_in[3];
    const float* phw   = (const float*)d_in[4];
    const float* phb   = (const float*)d_in[5];
    const float* pcw   = (const float*)d_in[6];
    const float* pcb   = (const float*)d_in[7];
    const float* wih0  = (const float*)d_in[8];
    const float* whh0  = (const float*)d_in[9];
    const float* b0    = (const float*)d_in[10];
    const float* wih1  = (const float*)d_in[11];
    const float* whh1  = (const float*)d_in[12];
    const float* b1    = (const float*)d_in[13];
    const float* fcw   = (const float*)d_in[14];
    const float* fcb   = (const float*)d_in[15];

    float* ws = (float*)d_ws;
    size_t off = 0;
    auto alloc = [&](size_t n) { float* p = ws + off; off += n; return p; };
    float* projhT   = alloc((size_t)ENC * H);
    float* projcT   = alloc((size_t)ENC * H);
    float* ctxT     = alloc((size_t)H * G4);
    float* xT       = alloc((size_t)E * G4);
    float* h0       = alloc((size_t)B * T1 * H);
    float* c0       = alloc((size_t)B * T1 * H);
    float* pre_ctxi = alloc((size_t)B * T1 * G4);
    float* pre_xi   = alloc((size_t)(SEG + 1) * B * T21 * G4);
    float* c1       = alloc((size_t)NCELL * H);
    float* c2       = alloc((size_t)NCELL * H);
    float* b1i      = alloc((size_t)G4);
    float* selbuf   = alloc((size_t)(SEG + 1) * NCELL);
    float* eospbuf  = alloc((size_t)(SEG + 1) * NCELL);
    float* pm       = alloc((size_t)NBV * NCELL);
    float* ps       = alloc((size_t)NBV * NCELL);
    int*   cnt      = (int*)alloc(128);
    short* hc0      = (short*)alloc((size_t)NCELL * 512 / 2);
    short* hc1      = (short*)alloc((size_t)NCELL * 512 / 2);
    short* h2buf    = (short*)alloc((size_t)NCELL * 256 / 2);
    short* whh0i    = (short*)alloc((size_t)G4 * 256 / 2);
    short* w1i      = (short*)alloc((size_t)G4 * 512 / 2);
    short* fcwbf    = (short*)alloc((size_t)V * H / 2);

    hipMemsetAsync(cnt, 0, 128 * sizeof(float), stream);

    hipLaunchKernelGGL(k_setup, dim3(14148), dim3(256), 0, stream,
                       fcw, whh0, wih1, whh1, phw, pcw, wih0, b1,
                       fcwbf, whh0i, w1i, projhT, projcT, ctxT, xT, b1i);
    hipLaunchKernelGGL(k_init_state, dim3(B * T1), dim3(256), 0, stream,
                       enc, projhT, phb, projcT, pcb, h0, c0);
    hipLaunchKernelGGL(k_init2, dim3(NCELL + 64 + (SEG + 1) * B * T21), dim3(256), 0, stream,
                       y, embed, se, h0, c0, ctxT, xT, b0, c1, c2, hc0, h2buf, pre_ctxi, pre_xi);

    short* hcb[2] = { hc0, hc1 };
    for (int s = 0; s <= SEG; ++s) {
        short* IN  = hcb[s & 1];
        short* OUT = hcb[1 - (s & 1)];
        hipLaunchKernelGGL((k_lstm<0>), dim3(NCELL / 64, 16), dim3(256), 0, stream,
                           s, IN, whh0i, pre_ctxi, pre_xi, b1i, c1, OUT, h2buf);
        hipLaunchKernelGGL((k_lstm<1>), dim3(NCELL / 64, 16), dim3(256), 0, stream,
                           s, OUT, w1i, pre_ctxi, pre_xi, b1i, c2, OUT, h2buf);
        hipLaunchKernelGGL(k_fc_score, dim3(NCELL / 64, NBV), dim3(256), 0, stream,
                           s, h2buf, fcwbf, fcb, y, pm, ps, selbuf, eospbuf, cnt + s * 17);
    }
    hipLaunchKernelGGL(k_dp, dim3(1), dim3(256), 0, stream, selbuf, eospbuf, (float*)d_out);
}

// Round 4
// 537.447 us; speedup vs baseline: 2.5676x; 2.5676x over previous
//
#include <hip/hip_runtime.h>
#include <math.h>

#define B 4
#define T1 16
#define T2 16
#define SEG 4
#define V 8000
#define E 256
#define H 256
#define ENC 512
#define EOS 2
#define NEGV -1e30f
#define G4 1024
#define NCELL 1088
#define NBV 125
#define T21 17

typedef __attribute__((ext_vector_type(4))) float f32x4;
typedef __attribute__((ext_vector_type(8))) short bf16x8;

__device__ __forceinline__ float sigm(float x) { return 1.f / (1.f + __expf(-x)); }
__device__ __forceinline__ float b2f(short x) {
    unsigned u = ((unsigned)(unsigned short)x) << 16;
    return __builtin_bit_cast(float, u);
}
__device__ __forceinline__ short f2b(float f) {
    unsigned u = __builtin_bit_cast(unsigned, f);
    unsigned r = (u + 0x7fffu + ((u >> 16) & 1u)) >> 16;
    return (short)r;
}

// ---------------- fused setup: casts / transposes / gate-interleave permutes ----------------
__global__ void k_setup(const float* __restrict__ fcw, const float* __restrict__ whh0,
                        const float* __restrict__ wih1, const float* __restrict__ whh1,
                        const float* __restrict__ phw, const float* __restrict__ pcw,
                        const float* __restrict__ wih0, const float* __restrict__ b1,
                        short* __restrict__ fcwbf, short* __restrict__ whh0i, short* __restrict__ w1i,
                        float* __restrict__ projhT, float* __restrict__ projcT,
                        float* __restrict__ ctxT, float* __restrict__ xT, float* __restrict__ b1i) {
    int bid = blockIdx.x, tid = threadIdx.x;
    if (bid < 8000) { int i = bid * 256 + tid; fcwbf[i] = f2b(fcw[i]); return; }
    bid -= 8000;
    if (bid < 1024) {
        int i = bid * 256 + tid; int gp = i >> 8, k = i & 255; int j = gp >> 2, gate = gp & 3;
        whh0i[i] = f2b(whh0[(size_t)(gate * 256 + j) * 256 + k]); return;
    }
    bid -= 1024;
    if (bid < 2048) {
        int i = bid * 256 + tid; int gp = i >> 9, k = i & 511; int j = gp >> 2, gate = gp & 3;
        float v = (k < 256) ? wih1[(size_t)(gate * 256 + j) * 256 + k]
                            : whh1[(size_t)(gate * 256 + j) * 256 + (k - 256)];
        w1i[i] = f2b(v); return;
    }
    bid -= 2048;
    if (bid < 512) { int i = bid * 256 + tid; int k = i >> 8, r = i & 255; projhT[i] = phw[(size_t)r * ENC + k]; return; }
    bid -= 512;
    if (bid < 512) { int i = bid * 256 + tid; int k = i >> 8, r = i & 255; projcT[i] = pcw[(size_t)r * ENC + k]; return; }
    bid -= 512;
    if (bid < 2048) {
        int i = bid * 256 + tid; int g = i >> 9, k = i & 511; float v = wih0[i];
        if (k < 256) ctxT[(size_t)k * G4 + g] = v; else xT[(size_t)(k - 256) * G4 + g] = v;
        return;
    }
    bid -= 2048;
    if (bid < 4) { int i = bid * 256 + tid; int j = i >> 2, gate = i & 3; b1i[i] = b1[gate * 256 + j]; return; }
}

// ---------------- h0/c0 = eo @ projT + b ----------------
__global__ void k_init_state(const float* __restrict__ enc, const float* __restrict__ phT,
                             const float* __restrict__ phb, const float* __restrict__ pcT,
                             const float* __restrict__ pcb, float* __restrict__ h0, float* __restrict__ c0) {
    __shared__ float eo[ENC];
    int bi = blockIdx.x;
    int b = bi / T1, i = bi % T1;
    int j = threadIdx.x;
    for (int e = j; e < ENC; e += 256) eo[e] = enc[(size_t)(i * B + b) * ENC + e];
    __syncthreads();
    float ha = phb[j], ca = pcb[j];
    for (int e = 0; e < ENC; ++e) {
        float x = eo[e];
        ha += x * phT[(size_t)e * H + j];
        ca += x * pcT[(size_t)e * H + j];
    }
    h0[(size_t)bi * H + j] = ha;
    c0[(size_t)bi * H + j] = ca;
}

// ---------------- fused init: state broadcast + pre_ctx + pre_x (interleaved gate layout) ----------------
__global__ void k_init2(const int* __restrict__ y, const float* __restrict__ embed, const float* __restrict__ se,
                        const float* __restrict__ h0, const float* __restrict__ c0,
                        const float* __restrict__ ctxT, const float* __restrict__ xT,
                        const float* __restrict__ b0,
                        float* __restrict__ c1, float* __restrict__ c2,
                        short* __restrict__ hc0, short* __restrict__ h2buf,
                        float* __restrict__ pre_ctxi, float* __restrict__ pre_xi) {
    __shared__ float sb[256];
    int bid = blockIdx.x, j = threadIdx.x;
    if (bid < NCELL) {
        int cell = bid, bi = cell / T21;
        c1[(size_t)cell * H + j] = c0[(size_t)bi * H + j];
        c2[(size_t)cell * H + j] = 0.f;
        hc0[(size_t)cell * 512 + j] = f2b(h0[(size_t)bi * H + j]);
        h2buf[(size_t)cell * H + j] = 0;
        return;
    }
    bid -= NCELL;
    if (bid < 64) {
        int bi = bid;
        sb[j] = h0[(size_t)bi * H + j];
        __syncthreads();
        float a0 = b0[j], a1 = b0[256 + j], a2 = b0[512 + j], a3 = b0[768 + j];
        for (int k = 0; k < H; ++k) {
            float x = sb[k];
            const float* w = ctxT + (size_t)k * G4;
            a0 += x * w[j]; a1 += x * w[256 + j]; a2 += x * w[512 + j]; a3 += x * w[768 + j];
        }
        *(float4*)&pre_ctxi[(size_t)bi * G4 + 4 * j] = make_float4(a0, a1, a2, a3);
        return;
    }
    bid -= 64;
    int row = bid;                    // (s*B + b)*T21 + t
    int s = row / (B * T21), rem = row % (B * T21);
    int b = rem / T21, t = rem % T21;
    const float* src;
    if (s == 0) src = se;
    else { int tt = t + s - 1; if (tt > 15) tt = 15; src = embed + (size_t)y[b * T2 + tt] * E; }
    sb[j] = src[j];
    __syncthreads();
    float a0 = 0, a1 = 0, a2 = 0, a3 = 0;
    for (int k = 0; k < E; ++k) {
        float x = sb[k];
        const float* w = xT + (size_t)k * G4;
        a0 += x * w[j]; a1 += x * w[256 + j]; a2 += x * w[512 + j]; a3 += x * w[768 + j];
    }
    *(float4*)&pre_xi[(size_t)row * G4 + 4 * j] = make_float4(a0, a1, a2, a3);
}

// ---------------- fused LSTM layer: MFMA GEMM (interleaved gates) + nonlinearity ----------------
template<int LAYER>
__global__ void k_lstm(int s, const short* __restrict__ A, const short* __restrict__ Bw,
                       const float* __restrict__ pre_ctxi, const float* __restrict__ pre_xi,
                       const float* __restrict__ b1i, float* __restrict__ cst,
                       short* __restrict__ OUT, short* __restrict__ h2buf) {
    constexpr int K = LAYER ? 512 : 256;
    __shared__ float sg[64][68];
    int tid = threadIdx.x;
    int wave = tid >> 6, lane = tid & 63, ln = lane & 15, kg = lane >> 4;
    int m0 = blockIdx.x * 64 + wave * 16;
    int n0 = blockIdx.y * 64;
    const short* Ap = A + (size_t)(m0 + ln) * 512 + kg * 8;
    const short* Bp = Bw + (size_t)(n0 + ln) * K + kg * 8;
    f32x4 acc[4] = {};
#pragma unroll
    for (int k = 0; k < K; k += 32) {
        bf16x8 a = *(const bf16x8*)(Ap + k);
#pragma unroll
        for (int nf = 0; nf < 4; ++nf) {
            bf16x8 b = *(const bf16x8*)(Bp + (size_t)nf * 16 * K + k);
            acc[nf] = __builtin_amdgcn_mfma_f32_16x16x32_bf16(a, b, acc[nf], 0, 0, 0);
        }
    }
#pragma unroll
    for (int nf = 0; nf < 4; ++nf)
#pragma unroll
        for (int r = 0; r < 4; ++r)
            sg[wave * 16 + kg * 4 + r][nf * 16 + ln] = acc[nf][r];
    __syncthreads();
    int jlo = n0 >> 2;
#pragma unroll
    for (int q = 0; q < 4; ++q) {
        int item = q * 256 + tid;
        int c = item >> 4, jj = item & 15;
        int cell = blockIdx.x * 64 + c;
        int j = jlo + jj;
        float4 g = *(float4*)&sg[c][4 * jj];
        float ig, fg, gg, og;
        if constexpr (LAYER == 0) {
            int bi = cell / T21;
            int b = bi >> 4;
            int t = cell % T21;
            int prow = (s * B + b) * T21 + t;
            float4 pc = *(const float4*)&pre_ctxi[(size_t)bi * G4 + 4 * j];
            float4 px = *(const float4*)&pre_xi[(size_t)prow * G4 + 4 * j];
            ig = g.x + pc.x + px.x; fg = g.y + pc.y + px.y;
            gg = g.z + pc.z + px.z; og = g.w + pc.w + px.w;
        } else {
            float4 bb = *(const float4*)&b1i[4 * j];
            ig = g.x + bb.x; fg = g.y + bb.y; gg = g.z + bb.z; og = g.w + bb.w;
        }
        float cold = cst[(size_t)cell * H + j];
        float cn = sigm(fg) * cold + sigm(ig) * tanhf(gg);
        float hn = sigm(og) * tanhf(cn);
        cst[(size_t)cell * H + j] = cn;
        if constexpr (LAYER == 0) {
            OUT[(size_t)cell * 512 + j] = f2b(hn);
            OUT[(size_t)cell * 512 + 256 + j] = h2buf[(size_t)cell * H + j];
        } else {
            h2buf[(size_t)cell * H + j] = f2b(hn);
        }
    }
}

// ---------------- fc GEMM + fused online LSE partials (NO fences, NO atomics) ----------------
// grid (17, 125), block 256; A = h2buf [NCELL][256] bf16
__global__ void k_fc_mfma(const short* __restrict__ h2buf, const short* __restrict__ Wv,
                          const float* __restrict__ fcb,
                          float* __restrict__ pm, float* __restrict__ ps) {
    int tid = threadIdx.x;
    int wave = tid >> 6, lane = tid & 63, ln = lane & 15, kg = lane >> 4;
    int m0 = blockIdx.x * 64 + wave * 16;
    int n0 = blockIdx.y * 64;
    const short* Ap = h2buf + (size_t)(m0 + ln) * 256 + kg * 8;
    const short* Bp = Wv + (size_t)(n0 + ln) * 256 + kg * 8;
    f32x4 acc[4] = {};
#pragma unroll
    for (int k = 0; k < 256; k += 32) {
        bf16x8 a = *(const bf16x8*)(Ap + k);
#pragma unroll
        for (int nf = 0; nf < 4; ++nf) {
            bf16x8 b = *(const bf16x8*)(Bp + (size_t)nf * 16 * 256 + k);
            acc[nf] = __builtin_amdgcn_mfma_f32_16x16x32_bf16(a, b, acc[nf], 0, 0, 0);
        }
    }
    float m_[4], s_[4];
#pragma unroll
    for (int r = 0; r < 4; ++r) { m_[r] = -3.4e38f; s_[r] = 0.f; }
#pragma unroll
    for (int nf = 0; nf < 4; ++nf) {
        float fb = fcb[n0 + nf * 16 + ln];
#pragma unroll
        for (int r = 0; r < 4; ++r) {
            float v = acc[nf][r] + fb;
            float M = fmaxf(m_[r], v);
            s_[r] = s_[r] * __expf(m_[r] - M) + __expf(v - M);
            m_[r] = M;
        }
    }
#pragma unroll
    for (int mask = 1; mask < 16; mask <<= 1) {
#pragma unroll
        for (int r = 0; r < 4; ++r) {
            float om = __shfl_xor(m_[r], mask);
            float os = __shfl_xor(s_[r], mask);
            float M = fmaxf(m_[r], om);
            s_[r] = s_[r] * __expf(m_[r] - M) + os * __expf(om - M);
            m_[r] = M;
        }
    }
    if (ln == 0) {
#pragma unroll
        for (int r = 0; r < 4; ++r) {
            int cell = m0 + kg * 4 + r;
            pm[(size_t)blockIdx.y * NCELL + cell] = m_[r];
            ps[(size_t)blockIdx.y * NCELL + cell] = s_[r];
        }
    }
}

// ---------------- combine: tgt/EOS dots + 125-partial LSE -> sel/eosp ----------------
// grid (17), block 256; 4 threads per cell
__global__ void k_combine(int s, const short* __restrict__ h2buf, const short* __restrict__ Wv,
                          const float* __restrict__ fcb, const int* __restrict__ y,
                          const float* __restrict__ pm, const float* __restrict__ ps,
                          float* __restrict__ sel, float* __restrict__ eosp) {
    int tid = threadIdx.x;
    int cl = tid >> 2, q = tid & 3;
    int cell = blockIdx.x * 64 + cl;
    int b = cell / (T1 * T21);
    int t = cell % T21;
    int tv = 0;
    if (s < SEG) { int tt = t + s; if (tt > 15) tt = 15; tv = y[b * T2 + tt]; }
    const short* hp = h2buf + (size_t)cell * 256 + q * 64;
    const short* w1 = Wv + (size_t)tv * 256 + q * 64;
    const short* w2 = Wv + (size_t)EOS * 256 + q * 64;
    float d1 = 0.f, d2 = 0.f;
#pragma unroll
    for (int u = 0; u < 8; ++u) {
        bf16x8 av  = *(const bf16x8*)(hp + u * 8);
        bf16x8 wv1 = *(const bf16x8*)(w1 + u * 8);
        bf16x8 wv2 = *(const bf16x8*)(w2 + u * 8);
#pragma unroll
        for (int e = 0; e < 8; ++e) {
            float a = b2f(av[e]);
            d1 += a * b2f(wv1[e]);
            d2 += a * b2f(wv2[e]);
        }
    }
    d1 += __shfl_xor(d1, 1); d1 += __shfl_xor(d1, 2);
    d2 += __shfl_xor(d2, 1); d2 += __shfl_xor(d2, 2);
    float mm = -3.4e38f, ss = 0.f;
    for (int v2 = q * 32; v2 < q * 32 + 32 && v2 < NBV; ++v2) {
        float om = pm[(size_t)v2 * NCELL + cell], os = ps[(size_t)v2 * NCELL + cell];
        float M = fmaxf(mm, om);
        ss = ss * __expf(mm - M) + os * __expf(om - M);
        mm = M;
    }
#pragma unroll
    for (int d = 1; d < 4; d <<= 1) {
        float om = __shfl_xor(mm, d), os = __shfl_xor(ss, d);
        float M = fmaxf(mm, om);
        ss = ss * __expf(mm - M) + os * __expf(om - M);
        mm = M;
    }
    if (q == 0) {
        float lse = mm + __logf(ss);
        sel[s * NCELL + cell]  = d1 + fcb[tv]  - lse;
        eosp[s * NCELL + cell] = d2 + fcb[EOS] - lse;
    }
}

// ---------------- final DP, fully LDS-resident ----------------
__global__ void k_dp(const float* __restrict__ sel, const float* __restrict__ eosp, float* __restrict__ out) {
    __shared__ float row[SEG + 1][NCELL];
    __shared__ float alpha[B][T21];
    int tid = threadIdx.x;
    for (int c = tid; c < NCELL; c += 256) {
        float cum = 0.f;
        row[0][c] = eosp[c];
#pragma unroll
        for (int j = 1; j <= SEG; ++j) {
            cum += sel[(j - 1) * NCELL + c];
            row[j][c] = cum + eosp[j * NCELL + c];
        }
    }
    int b = tid / T21, t = tid % T21;
    bool act = tid < B * T21;
    if (act) alpha[b][t] = (t == 0) ? 0.f : NEGV;
    __syncthreads();
    for (int i = 0; i < T1; ++i) {
        float val = NEGV;
        if (act) {
            float terms[SEG + 1];
            float mx = -3.4e38f;
            int cnt2 = 0;
            for (int j = 0; j <= SEG && j <= t; ++j) {
                int cell = (b * T1 + i) * T21 + (t - j);
                float term = alpha[b][t - j] + row[j][cell];
                terms[cnt2++] = term;
                mx = fmaxf(mx, term);
            }
            float ssum = 0.f;
            for (int k2 = 0; k2 < cnt2; ++k2) ssum += __expf(terms[k2] - mx);
            val = mx + __logf(ssum);
        }
        __syncthreads();
        if (act) alpha[b][t] = val;
        __syncthreads();
    }
    if (act && t == T2) out[b] = alpha[b][T2];
}

extern "C" void kernel_launch(void* const* d_in, const int* in_sizes, int n_in,
                              void* d_out, int out_size, void* d_ws, size_t ws_size,
                              hipStream_t stream) {
    const int*   y     = (const int*)d_in[0];
    const float* enc   = (const float*)d_in[1];
    const float* embed = (const float*)d_in[2];
    const float* se    = (const float*)d_in[3];
    const float* phw   = (const float*)d_in[4];
    const float* phb   = (const float*)d_in[5];
    const float* pcw   = (const float*)d_in[6];
    const float* pcb   = (const float*)d_in[7];
    const float* wih0  = (const float*)d_in[8];
    const float* whh0  = (const float*)d_in[9];
    const float* b0    = (const float*)d_in[10];
    const float* wih1  = (const float*)d_in[11];
    const float* whh1  = (const float*)d_in[12];
    const float* b1    = (const float*)d_in[13];
    const float* fcw   = (const float*)d_in[14];
    const float* fcb   = (const float*)d_in[15];

    float* ws = (float*)d_ws;
    size_t off = 0;
    auto alloc = [&](size_t n) { float* p = ws + off; off += n; return p; };
    float* projhT   = alloc((size_t)ENC * H);
    float* projcT   = alloc((size_t)ENC * H);
    float* ctxT     = alloc((size_t)H * G4);
    float* xT       = alloc((size_t)E * G4);
    float* h0       = alloc((size_t)B * T1 * H);
    float* c0       = alloc((size_t)B * T1 * H);
    float* pre_ctxi = alloc((size_t)B * T1 * G4);
    float* pre_xi   = alloc((size_t)(SEG + 1) * B * T21 * G4);
    float* c1       = alloc((size_t)NCELL * H);
    float* c2       = alloc((size_t)NCELL * H);
    float* b1i      = alloc((size_t)G4);
    float* selbuf   = alloc((size_t)(SEG + 1) * NCELL);
    float* eospbuf  = alloc((size_t)(SEG + 1) * NCELL);
    float* pm       = alloc((size_t)NBV * NCELL);
    float* ps       = alloc((size_t)NBV * NCELL);
    short* hc0      = (short*)alloc((size_t)NCELL * 512 / 2);
    short* hc1      = (short*)alloc((size_t)NCELL * 512 / 2);
    short* h2buf    = (short*)alloc((size_t)NCELL * 256 / 2);
    short* whh0i    = (short*)alloc((size_t)G4 * 256 / 2);
    short* w1i      = (short*)alloc((size_t)G4 * 512 / 2);
    short* fcwbf    = (short*)alloc((size_t)V * H / 2);

    hipLaunchKernelGGL(k_setup, dim3(14148), dim3(256), 0, stream,
                       fcw, whh0, wih1, whh1, phw, pcw, wih0, b1,
                       fcwbf, whh0i, w1i, projhT, projcT, ctxT, xT, b1i);
    hipLaunchKernelGGL(k_init_state, dim3(B * T1), dim3(256), 0, stream,
                       enc, projhT, phb, projcT, pcb, h0, c0);
    hipLaunchKernelGGL(k_init2, dim3(NCELL + 64 + (SEG + 1) * B * T21), dim3(256), 0, stream,
                       y, embed, se, h0, c0, ctxT, xT, b0, c1, c2, hc0, h2buf, pre_ctxi, pre_xi);

    short* hcb[2] = { hc0, hc1 };
    for (int s = 0; s <= SEG; ++s) {
        short* IN  = hcb[s & 1];
        short* OUT = hcb[1 - (s & 1)];
        hipLaunchKernelGGL((k_lstm<0>), dim3(NCELL / 64, 16), dim3(256), 0, stream,
                           s, IN, whh0i, pre_ctxi, pre_xi, b1i, c1, OUT, h2buf);
        hipLaunchKernelGGL((k_lstm<1>), dim3(NCELL / 64, 16), dim3(256), 0, stream,
                           s, OUT, w1i, pre_ctxi, pre_xi, b1i, c2, OUT, h2buf);
        hipLaunchKernelGGL(k_fc_mfma, dim3(NCELL / 64, NBV), dim3(256), 0, stream,
                           h2buf, fcwbf, fcb, pm, ps);
        hipLaunchKernelGGL(k_combine, dim3(NCELL / 64), dim3(256), 0, stream,
                           s, h2buf, fcwbf, fcb, y, pm, ps, selbuf, eospbuf);
    }
    hipLaunchKernelGGL(k_dp, dim3(1), dim3(256), 0, stream, selbuf, eospbuf, (float*)d_out);
}

// Round 5
// 451.715 us; speedup vs baseline: 3.0549x; 1.1898x over previous
//
#include <hip/hip_runtime.h>
#include <math.h>

#define B 4
#define T1 16
#define T2 16
#define SEG 4
#define V 8000
#define E 256
#define H 256
#define ENC 512
#define EOS 2
#define NEGV -1e30f
#define G4 1024
#define NCELL 1088
#define NBV 125
#define T21 17

typedef __attribute__((ext_vector_type(4))) float f32x4;
typedef __attribute__((ext_vector_type(8))) short bf16x8;

__device__ __forceinline__ float sigm(float x) { return 1.f / (1.f + __expf(-x)); }
__device__ __forceinline__ float b2f(short x) {
    unsigned u = ((unsigned)(unsigned short)x) << 16;
    return __builtin_bit_cast(float, u);
}
__device__ __forceinline__ short f2b(float f) {
    unsigned u = __builtin_bit_cast(unsigned, f);
    unsigned r = (u + 0x7fffu + ((u >> 16) & 1u)) >> 16;
    return (short)r;
}

// ---------------- fused setup: casts / transposes / gate-interleave permutes ----------------
__global__ void k_setup(const float* __restrict__ fcw, const float* __restrict__ whh0,
                        const float* __restrict__ wih1, const float* __restrict__ whh1,
                        const float* __restrict__ phw, const float* __restrict__ pcw,
                        const float* __restrict__ wih0, const float* __restrict__ b1,
                        short* __restrict__ fcwbf, short* __restrict__ whh0i, short* __restrict__ w1i,
                        float* __restrict__ projhT, float* __restrict__ projcT,
                        float* __restrict__ ctxT, float* __restrict__ xT, float* __restrict__ b1i) {
    int bid = blockIdx.x, tid = threadIdx.x;
    if (bid < 8000) { int i = bid * 256 + tid; fcwbf[i] = f2b(fcw[i]); return; }
    bid -= 8000;
    if (bid < 1024) {
        int i = bid * 256 + tid; int gp = i >> 8, k = i & 255; int j = gp >> 2, gate = gp & 3;
        whh0i[i] = f2b(whh0[(size_t)(gate * 256 + j) * 256 + k]); return;
    }
    bid -= 1024;
    if (bid < 2048) {
        int i = bid * 256 + tid; int gp = i >> 9, k = i & 511; int j = gp >> 2, gate = gp & 3;
        float v = (k < 256) ? wih1[(size_t)(gate * 256 + j) * 256 + k]
                            : whh1[(size_t)(gate * 256 + j) * 256 + (k - 256)];
        w1i[i] = f2b(v); return;
    }
    bid -= 2048;
    if (bid < 512) { int i = bid * 256 + tid; int k = i >> 8, r = i & 255; projhT[i] = phw[(size_t)r * ENC + k]; return; }
    bid -= 512;
    if (bid < 512) { int i = bid * 256 + tid; int k = i >> 8, r = i & 255; projcT[i] = pcw[(size_t)r * ENC + k]; return; }
    bid -= 512;
    if (bid < 2048) {
        int i = bid * 256 + tid; int g = i >> 9, k = i & 511; float v = wih0[i];
        if (k < 256) ctxT[(size_t)k * G4 + g] = v; else xT[(size_t)(k - 256) * G4 + g] = v;
        return;
    }
    bid -= 2048;
    if (bid < 4) { int i = bid * 256 + tid; int j = i >> 2, gate = i & 3; b1i[i] = b1[gate * 256 + j]; return; }
}

// ---------------- h0/c0 = eo @ projT + b ----------------
__global__ void k_init_state(const float* __restrict__ enc, const float* __restrict__ phT,
                             const float* __restrict__ phb, const float* __restrict__ pcT,
                             const float* __restrict__ pcb, float* __restrict__ h0, float* __restrict__ c0) {
    __shared__ float eo[ENC];
    int bi = blockIdx.x;
    int b = bi / T1, i = bi % T1;
    int j = threadIdx.x;
    for (int e = j; e < ENC; e += 256) eo[e] = enc[(size_t)(i * B + b) * ENC + e];
    __syncthreads();
    float ha = phb[j], ca = pcb[j];
    for (int e = 0; e < ENC; ++e) {
        float x = eo[e];
        ha += x * phT[(size_t)e * H + j];
        ca += x * pcT[(size_t)e * H + j];
    }
    h0[(size_t)bi * H + j] = ha;
    c0[(size_t)bi * H + j] = ca;
}

// ---------------- fused init: state broadcast + pre_ctx + pre_x (interleaved gate layout) ----------------
__global__ void k_init2(const int* __restrict__ y, const float* __restrict__ embed, const float* __restrict__ se,
                        const float* __restrict__ h0, const float* __restrict__ c0,
                        const float* __restrict__ ctxT, const float* __restrict__ xT,
                        const float* __restrict__ b0,
                        float* __restrict__ c1, float* __restrict__ c2,
                        short* __restrict__ hc0, short* __restrict__ h2buf,
                        float* __restrict__ pre_ctxi, float* __restrict__ pre_xi) {
    __shared__ float sb[256];
    int bid = blockIdx.x, j = threadIdx.x;
    if (bid < NCELL) {
        int cell = bid, bi = cell / T21;
        c1[(size_t)cell * H + j] = c0[(size_t)bi * H + j];
        c2[(size_t)cell * H + j] = 0.f;
        hc0[(size_t)cell * 512 + j] = f2b(h0[(size_t)bi * H + j]);
        h2buf[(size_t)cell * H + j] = 0;
        return;
    }
    bid -= NCELL;
    if (bid < 64) {
        int bi = bid;
        sb[j] = h0[(size_t)bi * H + j];
        __syncthreads();
        float a0 = b0[j], a1 = b0[256 + j], a2 = b0[512 + j], a3 = b0[768 + j];
        for (int k = 0; k < H; ++k) {
            float x = sb[k];
            const float* w = ctxT + (size_t)k * G4;
            a0 += x * w[j]; a1 += x * w[256 + j]; a2 += x * w[512 + j]; a3 += x * w[768 + j];
        }
        *(float4*)&pre_ctxi[(size_t)bi * G4 + 4 * j] = make_float4(a0, a1, a2, a3);
        return;
    }
    bid -= 64;
    int row = bid;                    // (s*B + b)*T21 + t
    int s = row / (B * T21), rem = row % (B * T21);
    int b = rem / T21, t = rem % T21;
    const float* src;
    if (s == 0) src = se;
    else { int tt = t + s - 1; if (tt > 15) tt = 15; src = embed + (size_t)y[b * T2 + tt] * E; }
    sb[j] = src[j];
    __syncthreads();
    float a0 = 0, a1 = 0, a2 = 0, a3 = 0;
    for (int k = 0; k < E; ++k) {
        float x = sb[k];
        const float* w = xT + (size_t)k * G4;
        a0 += x * w[j]; a1 += x * w[256 + j]; a2 += x * w[512 + j]; a3 += x * w[768 + j];
    }
    *(float4*)&pre_xi[(size_t)row * G4 + 4 * j] = make_float4(a0, a1, a2, a3);
}

// ---------------- fused LSTM layer: single-wave 64Mx64N MFMA GEMM + nonlinearity ----------------
// grid (17, 16), block 64 (1 wave). Interleaved gate layout (col = 4*j + gate).
template<int LAYER>
__global__ __launch_bounds__(64, 4) void k_lstm(int s, const short* __restrict__ A, const short* __restrict__ Bw,
                       const float* __restrict__ pre_ctxi, const float* __restrict__ pre_xi,
                       const float* __restrict__ b1i, float* __restrict__ cst,
                       short* __restrict__ OUT, short* __restrict__ h2buf) {
    constexpr int K = LAYER ? 512 : 256;
    __shared__ float sg[64][69];
    int lane = threadIdx.x;
    int ln = lane & 15, kg = lane >> 4;
    int m0 = blockIdx.x * 64;
    int n0 = blockIdx.y * 64;
    const short* Ap = A + (size_t)(m0 + ln) * 512 + kg * 8;
    const short* Bp = Bw + (size_t)(n0 + ln) * K + kg * 8;
    f32x4 acc[4][4] = {};
#pragma unroll
    for (int k = 0; k < K; k += 32) {
        bf16x8 a[4], b[4];
#pragma unroll
        for (int mf = 0; mf < 4; ++mf) a[mf] = *(const bf16x8*)(Ap + (size_t)mf * 16 * 512 + k);
#pragma unroll
        for (int nf = 0; nf < 4; ++nf) b[nf] = *(const bf16x8*)(Bp + (size_t)nf * 16 * K + k);
#pragma unroll
        for (int mf = 0; mf < 4; ++mf)
#pragma unroll
            for (int nf = 0; nf < 4; ++nf)
                acc[mf][nf] = __builtin_amdgcn_mfma_f32_16x16x32_bf16(a[mf], b[nf], acc[mf][nf], 0, 0, 0);
    }
#pragma unroll
    for (int mf = 0; mf < 4; ++mf)
#pragma unroll
        for (int nf = 0; nf < 4; ++nf)
#pragma unroll
            for (int r = 0; r < 4; ++r)
                sg[mf * 16 + kg * 4 + r][nf * 16 + ln] = acc[mf][nf][r];
    __syncthreads();
    // epilogue: thread = cell, 16 interleaved j's
    int cell = m0 + lane;
    int jlo = n0 >> 2;
    int bi = cell / T21;
    int bb = bi >> 4;
    int t = cell % T21;
    int prow = (s * B + bb) * T21 + t;
#pragma unroll
    for (int jj = 0; jj < 16; ++jj) {
        int j = jlo + jj;
        float gi = sg[lane][4 * jj], gf = sg[lane][4 * jj + 1];
        float gz = sg[lane][4 * jj + 2], go = sg[lane][4 * jj + 3];
        float ig, fg, gg, og;
        if constexpr (LAYER == 0) {
            float4 pc = *(const float4*)&pre_ctxi[(size_t)bi * G4 + 4 * j];
            float4 px = *(const float4*)&pre_xi[(size_t)prow * G4 + 4 * j];
            ig = gi + pc.x + px.x; fg = gf + pc.y + px.y;
            gg = gz + pc.z + px.z; og = go + pc.w + px.w;
        } else {
            float4 bv = *(const float4*)&b1i[4 * j];
            ig = gi + bv.x; fg = gf + bv.y; gg = gz + bv.z; og = go + bv.w;
        }
        float cold = cst[(size_t)cell * H + j];
        float cn = sigm(fg) * cold + sigm(ig) * tanhf(gg);
        float hn = sigm(og) * tanhf(cn);
        cst[(size_t)cell * H + j] = cn;
        if constexpr (LAYER == 0) {
            OUT[(size_t)cell * 512 + j] = f2b(hn);
            OUT[(size_t)cell * 512 + 256 + j] = h2buf[(size_t)cell * H + j];
        } else {
            h2buf[(size_t)cell * H + j] = f2b(hn);
        }
    }
}

// ---------------- fc: single-wave 64Mx64N MFMA GEMM + fused online LSE partials ----------------
// grid (17, 125), block 64 (1 wave)
__global__ __launch_bounds__(64, 4) void k_fc_mfma(const short* __restrict__ h2buf, const short* __restrict__ Wv,
                          const float* __restrict__ fcb,
                          float* __restrict__ pm, float* __restrict__ ps) {
    int lane = threadIdx.x;
    int ln = lane & 15, kg = lane >> 4;
    int m0 = blockIdx.x * 64;
    int n0 = blockIdx.y * 64;
    const short* Ap = h2buf + (size_t)(m0 + ln) * 256 + kg * 8;
    const short* Bp = Wv + (size_t)(n0 + ln) * 256 + kg * 8;
    f32x4 acc[4][4] = {};
#pragma unroll
    for (int k = 0; k < 256; k += 32) {
        bf16x8 a[4], b[4];
#pragma unroll
        for (int mf = 0; mf < 4; ++mf) a[mf] = *(const bf16x8*)(Ap + (size_t)mf * 16 * 256 + k);
#pragma unroll
        for (int nf = 0; nf < 4; ++nf) b[nf] = *(const bf16x8*)(Bp + (size_t)nf * 16 * 256 + k);
#pragma unroll
        for (int mf = 0; mf < 4; ++mf)
#pragma unroll
            for (int nf = 0; nf < 4; ++nf)
                acc[mf][nf] = __builtin_amdgcn_mfma_f32_16x16x32_bf16(a[mf], b[nf], acc[mf][nf], 0, 0, 0);
    }
    float fb = fcb[n0 + ln];        // col for nf=0; per-nf below
    float m_[4][4], s_[4][4];
#pragma unroll
    for (int mf = 0; mf < 4; ++mf)
#pragma unroll
        for (int r = 0; r < 4; ++r) { m_[mf][r] = -3.4e38f; s_[mf][r] = 0.f; }
#pragma unroll
    for (int nf = 0; nf < 4; ++nf) {
        float fbn = fcb[n0 + nf * 16 + ln];
#pragma unroll
        for (int mf = 0; mf < 4; ++mf)
#pragma unroll
            for (int r = 0; r < 4; ++r) {
                float v = acc[mf][nf][r] + fbn;
                float M = fmaxf(m_[mf][r], v);
                s_[mf][r] = s_[mf][r] * __expf(m_[mf][r] - M) + __expf(v - M);
                m_[mf][r] = M;
            }
    }
    (void)fb;
#pragma unroll
    for (int mask = 1; mask < 16; mask <<= 1) {
#pragma unroll
        for (int mf = 0; mf < 4; ++mf)
#pragma unroll
            for (int r = 0; r < 4; ++r) {
                float om = __shfl_xor(m_[mf][r], mask);
                float os = __shfl_xor(s_[mf][r], mask);
                float M = fmaxf(m_[mf][r], om);
                s_[mf][r] = s_[mf][r] * __expf(m_[mf][r] - M) + os * __expf(om - M);
                m_[mf][r] = M;
            }
    }
    if (ln == 0) {
#pragma unroll
        for (int mf = 0; mf < 4; ++mf)
#pragma unroll
            for (int r = 0; r < 4; ++r) {
                int cell = m0 + mf * 16 + kg * 4 + r;
                pm[(size_t)blockIdx.y * NCELL + cell] = m_[mf][r];
                ps[(size_t)blockIdx.y * NCELL + cell] = s_[mf][r];
            }
    }
}

// ---------------- combine: tgt/EOS dots + 125-partial LSE -> sel/eosp ----------------
// grid (17), block 256; 4 threads per cell
__global__ void k_combine(int s, const short* __restrict__ h2buf, const short* __restrict__ Wv,
                          const float* __restrict__ fcb, const int* __restrict__ y,
                          const float* __restrict__ pm, const float* __restrict__ ps,
                          float* __restrict__ sel, float* __restrict__ eosp) {
    int tid = threadIdx.x;
    int cl = tid >> 2, q = tid & 3;
    int cell = blockIdx.x * 64 + cl;
    int b = cell / (T1 * T21);
    int t = cell % T21;
    int tv = 0;
    if (s < SEG) { int tt = t + s; if (tt > 15) tt = 15; tv = y[b * T2 + tt]; }
    const short* hp = h2buf + (size_t)cell * 256 + q * 64;
    const short* w1 = Wv + (size_t)tv * 256 + q * 64;
    const short* w2 = Wv + (size_t)EOS * 256 + q * 64;
    float d1 = 0.f, d2 = 0.f;
#pragma unroll
    for (int u = 0; u < 8; ++u) {
        bf16x8 av  = *(const bf16x8*)(hp + u * 8);
        bf16x8 wv1 = *(const bf16x8*)(w1 + u * 8);
        bf16x8 wv2 = *(const bf16x8*)(w2 + u * 8);
#pragma unroll
        for (int e = 0; e < 8; ++e) {
            float a = b2f(av[e]);
            d1 += a * b2f(wv1[e]);
            d2 += a * b2f(wv2[e]);
        }
    }
    d1 += __shfl_xor(d1, 1); d1 += __shfl_xor(d1, 2);
    d2 += __shfl_xor(d2, 1); d2 += __shfl_xor(d2, 2);
    float mm = -3.4e38f, ss = 0.f;
    for (int v2 = q * 32; v2 < q * 32 + 32 && v2 < NBV; ++v2) {
        float om = pm[(size_t)v2 * NCELL + cell], os = ps[(size_t)v2 * NCELL + cell];
        float M = fmaxf(mm, om);
        ss = ss * __expf(mm - M) + os * __expf(om - M);
        mm = M;
    }
#pragma unroll
    for (int d = 1; d < 4; d <<= 1) {
        float om = __shfl_xor(mm, d), os = __shfl_xor(ss, d);
        float M = fmaxf(mm, om);
        ss = ss * __expf(mm - M) + os * __expf(om - M);
        mm = M;
    }
    if (q == 0) {
        float lse = mm + __logf(ss);
        sel[s * NCELL + cell]  = d1 + fcb[tv]  - lse;
        eosp[s * NCELL + cell] = d2 + fcb[EOS] - lse;
    }
}

// ---------------- final DP, fully LDS-resident ----------------
__global__ void k_dp(const float* __restrict__ sel, const float* __restrict__ eosp, float* __restrict__ out) {
    __shared__ float row[SEG + 1][NCELL];
    __shared__ float alpha[B][T21];
    int tid = threadIdx.x;
    for (int c = tid; c < NCELL; c += 256) {
        float cum = 0.f;
        row[0][c] = eosp[c];
#pragma unroll
        for (int j = 1; j <= SEG; ++j) {
            cum += sel[(j - 1) * NCELL + c];
            row[j][c] = cum + eosp[j * NCELL + c];
        }
    }
    int b = tid / T21, t = tid % T21;
    bool act = tid < B * T21;
    if (act) alpha[b][t] = (t == 0) ? 0.f : NEGV;
    __syncthreads();
    for (int i = 0; i < T1; ++i) {
        float val = NEGV;
        if (act) {
            float terms[SEG + 1];
            float mx = -3.4e38f;
            int cnt2 = 0;
            for (int j = 0; j <= SEG && j <= t; ++j) {
                int cell = (b * T1 + i) * T21 + (t - j);
                float term = alpha[b][t - j] + row[j][cell];
                terms[cnt2++] = term;
                mx = fmaxf(mx, term);
            }
            float ssum = 0.f;
            for (int k2 = 0; k2 < cnt2; ++k2) ssum += __expf(terms[k2] - mx);
            val = mx + __logf(ssum);
        }
        __syncthreads();
        if (act) alpha[b][t] = val;
        __syncthreads();
    }
    if (act && t == T2) out[b] = alpha[b][T2];
}

extern "C" void kernel_launch(void* const* d_in, const int* in_sizes, int n_in,
                              void* d_out, int out_size, void* d_ws, size_t ws_size,
                              hipStream_t stream) {
    const int*   y     = (const int*)d_in[0];
    const float* enc   = (const float*)d_in[1];
    const float* embed = (const float*)d_in[2];
    const float* se    = (const float*)d_in[3];
    const float* phw   = (const float*)d_in[4];
    const float* phb   = (const float*)d_in[5];
    const float* pcw   = (const float*)d_in[6];
    const float* pcb   = (const float*)d_in[7];
    const float* wih0  = (const float*)d_in[8];
    const float* whh0  = (const float*)d_in[9];
    const float* b0    = (const float*)d_in[10];
    const float* wih1  = (const float*)d_in[11];
    const float* whh1  = (const float*)d_in[12];
    const float* b1    = (const float*)d_in[13];
    const float* fcw   = (const float*)d_in[14];
    const float* fcb   = (const float*)d_in[15];

    float* ws = (float*)d_ws;
    size_t off = 0;
    auto alloc = [&](size_t n) { float* p = ws + off; off += n; return p; };
    float* projhT   = alloc((size_t)ENC * H);
    float* projcT   = alloc((size_t)ENC * H);
    float* ctxT     = alloc((size_t)H * G4);
    float* xT       = alloc((size_t)E * G4);
    float* h0       = alloc((size_t)B * T1 * H);
    float* c0       = alloc((size_t)B * T1 * H);
    float* pre_ctxi = alloc((size_t)B * T1 * G4);
    float* pre_xi   = alloc((size_t)(SEG + 1) * B * T21 * G4);
    float* c1       = alloc((size_t)NCELL * H);
    float* c2       = alloc((size_t)NCELL * H);
    float* b1i      = alloc((size_t)G4);
    float* selbuf   = alloc((size_t)(SEG + 1) * NCELL);
    float* eospbuf  = alloc((size_t)(SEG + 1) * NCELL);
    float* pm       = alloc((size_t)NBV * NCELL);
    float* ps       = alloc((size_t)NBV * NCELL);
    short* hc0      = (short*)alloc((size_t)NCELL * 512 / 2);
    short* hc1      = (short*)alloc((size_t)NCELL * 512 / 2);
    short* h2buf    = (short*)alloc((size_t)NCELL * 256 / 2);
    short* whh0i    = (short*)alloc((size_t)G4 * 256 / 2);
    short* w1i      = (short*)alloc((size_t)G4 * 512 / 2);
    short* fcwbf    = (short*)alloc((size_t)V * H / 2);

    hipLaunchKernelGGL(k_setup, dim3(14148), dim3(256), 0, stream,
                       fcw, whh0, wih1, whh1, phw, pcw, wih0, b1,
                       fcwbf, whh0i, w1i, projhT, projcT, ctxT, xT, b1i);
    hipLaunchKernelGGL(k_init_state, dim3(B * T1), dim3(256), 0, stream,
                       enc, projhT, phb, projcT, pcb, h0, c0);
    hipLaunchKernelGGL(k_init2, dim3(NCELL + 64 + (SEG + 1) * B * T21), dim3(256), 0, stream,
                       y, embed, se, h0, c0, ctxT, xT, b0, c1, c2, hc0, h2buf, pre_ctxi, pre_xi);

    short* hcb[2] = { hc0, hc1 };
    for (int s = 0; s <= SEG; ++s) {
        short* IN  = hcb[s & 1];
        short* OUT = hcb[1 - (s & 1)];
        hipLaunchKernelGGL((k_lstm<0>), dim3(17, 16), dim3(64), 0, stream,
                           s, IN, whh0i, pre_ctxi, pre_xi, b1i, c1, OUT, h2buf);
        hipLaunchKernelGGL((k_lstm<1>), dim3(17, 16), dim3(64), 0, stream,
                           s, OUT, w1i, pre_ctxi, pre_xi, b1i, c2, OUT, h2buf);
        hipLaunchKernelGGL(k_fc_mfma, dim3(17, NBV), dim3(64), 0, stream,
                           h2buf, fcwbf, fcb, pm, ps);
        hipLaunchKernelGGL(k_combine, dim3(17), dim3(256), 0, stream,
                           s, h2buf, fcwbf, fcb, y, pm, ps, selbuf, eospbuf);
    }
    hipLaunchKernelGGL(k_dp, dim3(1), dim3(256), 0, stream, selbuf, eospbuf, (float*)d_out);
}

// Round 6
// 439.228 us; speedup vs baseline: 3.1418x; 1.0284x over previous
//
#include <hip/hip_runtime.h>
#include <math.h>

#define B 4
#define T1 16
#define T2 16
#define SEG 4
#define V 8000
#define E 256
#define H 256
#define ENC 512
#define EOS 2
#define NEGV -1e30f
#define G4 1024
#define NCELL 1088
#define T21 17
#define NFC 2125   // 17*125 fc tiles
#define NL 272     // 17*16 lstm tiles

typedef __attribute__((ext_vector_type(4))) float f32x4;
typedef __attribute__((ext_vector_type(8))) short bf16x8;

__device__ __forceinline__ float sigm(float x) { return 1.f / (1.f + __expf(-x)); }
__device__ __forceinline__ float ftanh(float x) { float e = __expf(2.f * x); return 1.f - 2.f / (e + 1.f); }
__device__ __forceinline__ float b2f(short x) {
    unsigned u = ((unsigned)(unsigned short)x) << 16;
    return __builtin_bit_cast(float, u);
}
__device__ __forceinline__ short f2b(float f) {
    unsigned u = __builtin_bit_cast(unsigned, f);
    unsigned r = (u + 0x7fffu + ((u >> 16) & 1u)) >> 16;
    return (short)r;
}

// ---------------- fused setup: casts / transposes / gate-interleave permutes ----------------
__global__ void k_setup(const float* __restrict__ fcw, const float* __restrict__ whh0,
                        const float* __restrict__ wih1, const float* __restrict__ whh1,
                        const float* __restrict__ phw, const float* __restrict__ pcw,
                        const float* __restrict__ wih0, const float* __restrict__ b1,
                        short* __restrict__ fcwbf, short* __restrict__ whh0i, short* __restrict__ w1i,
                        float* __restrict__ projhT, float* __restrict__ projcT,
                        float* __restrict__ ctxT, float* __restrict__ xT, float* __restrict__ b1i) {
    int bid = blockIdx.x, tid = threadIdx.x;
    if (bid < 8000) { int i = bid * 256 + tid; fcwbf[i] = f2b(fcw[i]); return; }
    bid -= 8000;
    if (bid < 1024) {
        int i = bid * 256 + tid; int gp = i >> 8, k = i & 255; int j = gp >> 2, gate = gp & 3;
        whh0i[i] = f2b(whh0[(size_t)(gate * 256 + j) * 256 + k]); return;
    }
    bid -= 1024;
    if (bid < 2048) {
        int i = bid * 256 + tid; int gp = i >> 9, k = i & 511; int j = gp >> 2, gate = gp & 3;
        float v = (k < 256) ? wih1[(size_t)(gate * 256 + j) * 256 + k]
                            : whh1[(size_t)(gate * 256 + j) * 256 + (k - 256)];
        w1i[i] = f2b(v); return;
    }
    bid -= 2048;
    if (bid < 512) { int i = bid * 256 + tid; int k = i >> 8, r = i & 255; projhT[i] = phw[(size_t)r * ENC + k]; return; }
    bid -= 512;
    if (bid < 512) { int i = bid * 256 + tid; int k = i >> 8, r = i & 255; projcT[i] = pcw[(size_t)r * ENC + k]; return; }
    bid -= 512;
    if (bid < 2048) {
        int i = bid * 256 + tid; int g = i >> 9, k = i & 511; float v = wih0[i];
        if (k < 256) ctxT[(size_t)k * G4 + g] = v; else xT[(size_t)(k - 256) * G4 + g] = v;
        return;
    }
    bid -= 2048;
    if (bid < 4) { int i = bid * 256 + tid; int j = i >> 2, gate = i & 3; b1i[i] = b1[gate * 256 + j]; return; }
}

// ---------------- h0/c0 = eo @ projT + b ----------------
__global__ void k_init_state(const float* __restrict__ enc, const float* __restrict__ phT,
                             const float* __restrict__ phb, const float* __restrict__ pcT,
                             const float* __restrict__ pcb, float* __restrict__ h0, float* __restrict__ c0) {
    __shared__ float eo[ENC];
    int bi = blockIdx.x;
    int b = bi / T1, i = bi % T1;
    int j = threadIdx.x;
    for (int e = j; e < ENC; e += 256) eo[e] = enc[(size_t)(i * B + b) * ENC + e];
    __syncthreads();
    float ha = phb[j], ca = pcb[j];
    for (int e = 0; e < ENC; ++e) {
        float x = eo[e];
        ha += x * phT[(size_t)e * H + j];
        ca += x * pcT[(size_t)e * H + j];
    }
    h0[(size_t)bi * H + j] = ha;
    c0[(size_t)bi * H + j] = ca;
}

// ---------------- fused init: state bcast + pre_ctx + pre_x + zero lsesum ----------------
// blocks: [0,1088) bcast; [1088,1152) prectx; [1152,1492) prex; [1492,1514) zero lsesum
__global__ void k_init2(const int* __restrict__ y, const float* __restrict__ embed, const float* __restrict__ se,
                        const float* __restrict__ h0, const float* __restrict__ c0,
                        const float* __restrict__ ctxT, const float* __restrict__ xT,
                        const float* __restrict__ b0,
                        float* __restrict__ c1, float* __restrict__ c2,
                        short* __restrict__ hc0, short* __restrict__ h2b1,
                        float* __restrict__ pre_ctxi, float* __restrict__ pre_xi,
                        float* __restrict__ lsesum) {
    __shared__ float sb[256];
    int bid = blockIdx.x, j = threadIdx.x;
    if (bid < NCELL) {
        int cell = bid, bi = cell / T21;
        c1[(size_t)cell * H + j] = c0[(size_t)bi * H + j];
        c2[(size_t)cell * H + j] = 0.f;
        hc0[(size_t)cell * 512 + j] = f2b(h0[(size_t)bi * H + j]);
        h2b1[(size_t)cell * 256 + j] = 0;
        return;
    }
    bid -= NCELL;
    if (bid < 64) {
        int bi = bid;
        sb[j] = h0[(size_t)bi * H + j];
        __syncthreads();
        float a0 = b0[j], a1 = b0[256 + j], a2 = b0[512 + j], a3 = b0[768 + j];
        for (int k = 0; k < H; ++k) {
            float x = sb[k];
            const float* w = ctxT + (size_t)k * G4;
            a0 += x * w[j]; a1 += x * w[256 + j]; a2 += x * w[512 + j]; a3 += x * w[768 + j];
        }
        *(float4*)&pre_ctxi[(size_t)bi * G4 + 4 * j] = make_float4(a0, a1, a2, a3);
        return;
    }
    bid -= 64;
    if (bid < (SEG + 1) * B * T21) {
        int row = bid;                    // (s*B + b)*T21 + t
        int s = row / (B * T21), rem = row % (B * T21);
        int b = rem / T21, t = rem % T21;
        const float* src;
        if (s == 0) src = se;
        else { int tt = t + s - 1; if (tt > 15) tt = 15; src = embed + (size_t)y[b * T2 + tt] * E; }
        sb[j] = src[j];
        __syncthreads();
        float a0 = 0, a1 = 0, a2 = 0, a3 = 0;
        for (int k = 0; k < E; ++k) {
            float x = sb[k];
            const float* w = xT + (size_t)k * G4;
            a0 += x * w[j]; a1 += x * w[256 + j]; a2 += x * w[512 + j]; a3 += x * w[768 + j];
        }
        *(float4*)&pre_xi[(size_t)row * G4 + 4 * j] = make_float4(a0, a1, a2, a3);
        return;
    }
    bid -= (SEG + 1) * B * T21;
    int i = bid * 256 + j;
    if (i < (SEG + 1) * NCELL) lsesum[i] = 0.f;
}

// ---------------- device bodies ----------------

// fc tile: 64Mx64N, 4 waves n-split; max-free exp-sum -> one atomicAdd per row
__device__ __forceinline__ void fc_body(int s, int fcid, float* smem,
        const short* __restrict__ h2b, const short* __restrict__ Wv,
        const float* __restrict__ fcb, float* __restrict__ lsesum) {
    int tid = threadIdx.x;
    int wave = tid >> 6, lane = tid & 63, ln = lane & 15, kg = lane >> 4;
    int mb = fcid / 125, nb = fcid % 125;
    int m0 = mb * 64, n0 = nb * 64;
    const short* Ap = h2b + (size_t)(m0 + ln) * 256 + kg * 8;
    const short* Bp = Wv + (size_t)(n0 + wave * 16 + ln) * 256 + kg * 8;
    f32x4 acc[4] = {};
#pragma unroll
    for (int k = 0; k < 256; k += 32) {
        bf16x8 b = *(const bf16x8*)(Bp + k);
#pragma unroll
        for (int mf = 0; mf < 4; ++mf) {
            bf16x8 a = *(const bf16x8*)(Ap + (size_t)mf * 16 * 256 + k);
            acc[mf] = __builtin_amdgcn_mfma_f32_16x16x32_bf16(a, b, acc[mf], 0, 0, 0);
        }
    }
    float fbn = fcb[n0 + wave * 16 + ln];
    float sums[4][4];
#pragma unroll
    for (int mf = 0; mf < 4; ++mf)
#pragma unroll
        for (int r = 0; r < 4; ++r)
            sums[mf][r] = __expf(acc[mf][r] + fbn);
#pragma unroll
    for (int mask = 1; mask < 16; mask <<= 1)
#pragma unroll
        for (int mf = 0; mf < 4; ++mf)
#pragma unroll
            for (int r = 0; r < 4; ++r)
                sums[mf][r] += __shfl_xor(sums[mf][r], mask);
    if (ln == 0) {
#pragma unroll
        for (int mf = 0; mf < 4; ++mf)
#pragma unroll
            for (int r = 0; r < 4; ++r)
                smem[wave * 64 + mf * 16 + kg * 4 + r] = sums[mf][r];
    }
    __syncthreads();
    if (tid < 64) {
        float v = smem[tid] + smem[64 + tid] + smem[128 + tid] + smem[192 + tid];
        atomicAdd(&lsesum[(size_t)s * NCELL + m0 + tid], v);
    }
}

// lstm tile: 64Mx64N, 4 waves n-split, fused gate nonlinearity (interleaved gate layout)
template<int LAYER>
__device__ __forceinline__ void lstm_body(int s, int l, float* smem,
        const short* __restrict__ A, const short* __restrict__ Bw,
        const float* __restrict__ pre_ctxi, const float* __restrict__ pre_xi,
        const float* __restrict__ b1i, float* __restrict__ cst,
        short* __restrict__ OUT, const short* __restrict__ h2old, short* __restrict__ h2new) {
    constexpr int K = LAYER ? 512 : 256;
    int tid = threadIdx.x;
    int wave = tid >> 6, lane = tid & 63, ln = lane & 15, kg = lane >> 4;
    int mb = l >> 4, nb = l & 15;
    int m0 = mb * 64, n0 = nb * 64;
    const short* Ap = A + (size_t)(m0 + ln) * 512 + kg * 8;
    const short* Bp = Bw + (size_t)(n0 + wave * 16 + ln) * K + kg * 8;
    f32x4 acc[4] = {};
#pragma unroll
    for (int k = 0; k < K; k += 32) {
        bf16x8 b = *(const bf16x8*)(Bp + k);
#pragma unroll
        for (int mf = 0; mf < 4; ++mf) {
            bf16x8 a = *(const bf16x8*)(Ap + (size_t)mf * 16 * 512 + k);
            acc[mf] = __builtin_amdgcn_mfma_f32_16x16x32_bf16(a, b, acc[mf], 0, 0, 0);
        }
    }
#pragma unroll
    for (int mf = 0; mf < 4; ++mf)
#pragma unroll
        for (int r = 0; r < 4; ++r)
            smem[(mf * 16 + kg * 4 + r) * 68 + wave * 16 + ln] = acc[mf][r];
    __syncthreads();
    int jlo = nb * 16;
#pragma unroll
    for (int q = 0; q < 4; ++q) {
        int item = q * 256 + tid;
        int c = item >> 4, jj = item & 15;
        int cell = m0 + c;
        int j = jlo + jj;
        float4 g = *(float4*)&smem[c * 68 + 4 * jj];
        float ig, fg, gg, og;
        if constexpr (LAYER == 0) {
            int bi = cell / T21;
            int bb = bi >> 4;
            int t = cell % T21;
            int prow = (s * B + bb) * T21 + t;
            float4 pc = *(const float4*)&pre_ctxi[(size_t)bi * G4 + 4 * j];
            float4 px = *(const float4*)&pre_xi[(size_t)prow * G4 + 4 * j];
            ig = g.x + pc.x + px.x; fg = g.y + pc.y + px.y;
            gg = g.z + pc.z + px.z; og = g.w + pc.w + px.w;
        } else {
            float4 bv = *(const float4*)&b1i[4 * j];
            ig = g.x + bv.x; fg = g.y + bv.y; gg = g.z + bv.z; og = g.w + bv.w;
        }
        float cold = cst[(size_t)cell * H + j];
        float cn = sigm(fg) * cold + sigm(ig) * ftanh(gg);
        float hn = sigm(og) * ftanh(cn);
        cst[(size_t)cell * H + j] = cn;
        if constexpr (LAYER == 0) {
            OUT[(size_t)cell * 512 + j] = f2b(hn);
            OUT[(size_t)cell * 512 + 256 + j] = h2old[(size_t)cell * 256 + j];
        } else {
            h2new[(size_t)cell * 256 + j] = f2b(hn);
        }
    }
}

// combine: tgt/EOS dots + lse = log(lsesum)
__device__ __forceinline__ void combine_body(int s, int blk,
        const short* __restrict__ h2b, const short* __restrict__ Wv,
        const float* __restrict__ fcb, const int* __restrict__ y,
        const float* __restrict__ lsesum, float* __restrict__ sel, float* __restrict__ eosp) {
    int tid = threadIdx.x;
    int cl = tid >> 2, q = tid & 3;
    int cell = blk * 64 + cl;
    int b = cell / (T1 * T21);
    int t = cell % T21;
    int tv = 0;
    if (s < SEG) { int tt = t + s; if (tt > 15) tt = 15; tv = y[b * T2 + tt]; }
    const short* hp = h2b + (size_t)cell * 256 + q * 64;
    const short* w1 = Wv + (size_t)tv * 256 + q * 64;
    const short* w2 = Wv + (size_t)EOS * 256 + q * 64;
    float d1 = 0.f, d2 = 0.f;
#pragma unroll
    for (int u = 0; u < 8; ++u) {
        bf16x8 av  = *(const bf16x8*)(hp + u * 8);
        bf16x8 wv1 = *(const bf16x8*)(w1 + u * 8);
        bf16x8 wv2 = *(const bf16x8*)(w2 + u * 8);
#pragma unroll
        for (int e = 0; e < 8; ++e) {
            float a = b2f(av[e]);
            d1 += a * b2f(wv1[e]);
            d2 += a * b2f(wv2[e]);
        }
    }
    d1 += __shfl_xor(d1, 1); d1 += __shfl_xor(d1, 2);
    d2 += __shfl_xor(d2, 1); d2 += __shfl_xor(d2, 2);
    if (q == 0) {
        float lse = __logf(lsesum[(size_t)s * NCELL + cell]);
        sel[s * NCELL + cell]  = d1 + fcb[tv]  - lse;
        eosp[s * NCELL + cell] = d2 + fcb[EOS] - lse;
    }
}

// ---------------- merged kernels (role-split by blockIdx) ----------------
__global__ __launch_bounds__(256, 4) void k_fcl0(int s_fc, int s_l0, int nfc,
        const short* __restrict__ h2cur, const short* __restrict__ fcwbf,
        const float* __restrict__ fcb, float* __restrict__ lsesum,
        const short* __restrict__ IN, const short* __restrict__ whh0i,
        const float* __restrict__ pre_ctxi, const float* __restrict__ pre_xi,
        float* __restrict__ c1, short* __restrict__ OUT, const short* __restrict__ h2old) {
    __shared__ float smem[64 * 68];
    int bx = blockIdx.x;
    if (bx < nfc) fc_body(s_fc, bx, smem, h2cur, fcwbf, fcb, lsesum);
    else lstm_body<0>(s_l0, bx - nfc, smem, IN, whh0i, pre_ctxi, pre_xi, nullptr, c1, OUT, h2old, nullptr);
}

__global__ __launch_bounds__(256, 4) void k_cl1(int s_c, int s_l1, int ncmb,
        const short* __restrict__ h2c, const short* __restrict__ fcwbf,
        const float* __restrict__ fcb, const int* __restrict__ y,
        const float* __restrict__ lsesum, float* __restrict__ sel, float* __restrict__ eosp,
        const short* __restrict__ A1, const short* __restrict__ w1i,
        const float* __restrict__ b1i, float* __restrict__ c2, short* __restrict__ h2new) {
    __shared__ float smem[64 * 68];
    int bx = blockIdx.x;
    if (bx < ncmb) combine_body(s_c, bx, h2c, fcwbf, fcb, y, lsesum, sel, eosp);
    else lstm_body<1>(s_l1, bx - ncmb, smem, A1, w1i, nullptr, nullptr, b1i, c2, nullptr, nullptr, h2new);
}

// ---------------- final DP, fully LDS-resident ----------------
__global__ void k_dp(const float* __restrict__ sel, const float* __restrict__ eosp, float* __restrict__ out) {
    __shared__ float row[SEG + 1][NCELL];
    __shared__ float alpha[B][T21];
    int tid = threadIdx.x;
    for (int c = tid; c < NCELL; c += 256) {
        float cum = 0.f;
        row[0][c] = eosp[c];
#pragma unroll
        for (int j = 1; j <= SEG; ++j) {
            cum += sel[(j - 1) * NCELL + c];
            row[j][c] = cum + eosp[j * NCELL + c];
        }
    }
    int b = tid / T21, t = tid % T21;
    bool act = tid < B * T21;
    if (act) alpha[b][t] = (t == 0) ? 0.f : NEGV;
    __syncthreads();
    for (int i = 0; i < T1; ++i) {
        float val = NEGV;
        if (act) {
            float terms[SEG + 1];
            float mx = -3.4e38f;
            int cnt2 = 0;
            for (int j = 0; j <= SEG && j <= t; ++j) {
                int cell = (b * T1 + i) * T21 + (t - j);
                float term = alpha[b][t - j] + row[j][cell];
                terms[cnt2++] = term;
                mx = fmaxf(mx, term);
            }
            float ssum = 0.f;
            for (int k2 = 0; k2 < cnt2; ++k2) ssum += __expf(terms[k2] - mx);
            val = mx + __logf(ssum);
        }
        __syncthreads();
        if (act) alpha[b][t] = val;
        __syncthreads();
    }
    if (act && t == T2) out[b] = alpha[b][T2];
}

extern "C" void kernel_launch(void* const* d_in, const int* in_sizes, int n_in,
                              void* d_out, int out_size, void* d_ws, size_t ws_size,
                              hipStream_t stream) {
    const int*   y     = (const int*)d_in[0];
    const float* enc   = (const float*)d_in[1];
    const float* embed = (const float*)d_in[2];
    const float* se    = (const float*)d_in[3];
    const float* phw   = (const float*)d_in[4];
    const float* phb   = (const float*)d_in[5];
    const float* pcw   = (const float*)d_in[6];
    const float* pcb   = (const float*)d_in[7];
    const float* wih0  = (const float*)d_in[8];
    const float* whh0  = (const float*)d_in[9];
    const float* b0    = (const float*)d_in[10];
    const float* wih1  = (const float*)d_in[11];
    const float* whh1  = (const float*)d_in[12];
    const float* b1    = (const float*)d_in[13];
    const float* fcw   = (const float*)d_in[14];
    const float* fcb   = (const float*)d_in[15];

    float* ws = (float*)d_ws;
    size_t off = 0;
    auto alloc = [&](size_t n) { float* p = ws + off; off += n; return p; };
    float* projhT   = alloc((size_t)ENC * H);
    float* projcT   = alloc((size_t)ENC * H);
    float* ctxT     = alloc((size_t)H * G4);
    float* xT       = alloc((size_t)E * G4);
    float* h0       = alloc((size_t)B * T1 * H);
    float* c0       = alloc((size_t)B * T1 * H);
    float* pre_ctxi = alloc((size_t)B * T1 * G4);
    float* pre_xi   = alloc((size_t)(SEG + 1) * B * T21 * G4);
    float* c1       = alloc((size_t)NCELL * H);
    float* c2       = alloc((size_t)NCELL * H);
    float* b1i      = alloc((size_t)G4);
    float* selbuf   = alloc((size_t)(SEG + 1) * NCELL);
    float* eospbuf  = alloc((size_t)(SEG + 1) * NCELL);
    float* lsesum   = alloc((size_t)(SEG + 1) * NCELL);
    short* hc0      = (short*)alloc((size_t)NCELL * 512 / 2);
    short* hc1      = (short*)alloc((size_t)NCELL * 512 / 2);
    short* h2a      = (short*)alloc((size_t)NCELL * 256 / 2);
    short* h2bb     = (short*)alloc((size_t)NCELL * 256 / 2);
    short* whh0i    = (short*)alloc((size_t)G4 * 256 / 2);
    short* w1i      = (short*)alloc((size_t)G4 * 512 / 2);
    short* fcwbf    = (short*)alloc((size_t)V * H / 2);

    short* hcb[2] = { hc0, hc1 };
    short* h2b[2] = { h2a, h2bb };

    hipLaunchKernelGGL(k_setup, dim3(14148), dim3(256), 0, stream,
                       fcw, whh0, wih1, whh1, phw, pcw, wih0, b1,
                       fcwbf, whh0i, w1i, projhT, projcT, ctxT, xT, b1i);
    hipLaunchKernelGGL(k_init_state, dim3(B * T1), dim3(256), 0, stream,
                       enc, projhT, phb, projcT, pcb, h0, c0);
    hipLaunchKernelGGL(k_init2, dim3(NCELL + 64 + (SEG + 1) * B * T21 + 22), dim3(256), 0, stream,
                       y, embed, se, h0, c0, ctxT, xT, b0, c1, c2, hcb[0], h2b[1],
                       pre_ctxi, pre_xi, lsesum);

    // L0_0 (no fc blocks): IN=hcb[0], OUT=hcb[1], h2old=h2b[1] (zeros)
    hipLaunchKernelGGL(k_fcl0, dim3(NL), dim3(256), 0, stream,
                       0, 0, 0, h2b[0], fcwbf, fcb, lsesum,
                       hcb[0], whh0i, pre_ctxi, pre_xi, c1, hcb[1], h2b[1]);
    // L1_0 (no combine blocks): A=hcb[1], h2new=h2b[0]
    hipLaunchKernelGGL(k_cl1, dim3(NL), dim3(256), 0, stream,
                       0, 0, 0, h2b[0], fcwbf, fcb, y, lsesum, selbuf, eospbuf,
                       hcb[1], w1i, b1i, c2, h2b[0]);

    for (int s = 0; s < SEG; ++s) {
        int p  = s & 1;
        int p1 = (s + 1) & 1;
        // FC_s || L0_{s+1}:  L0_{s+1}: IN=hcb[p1], OUT=hcb[p], h2old=h2b[p]
        hipLaunchKernelGGL(k_fcl0, dim3(NFC + NL), dim3(256), 0, stream,
                           s, s + 1, NFC, h2b[p], fcwbf, fcb, lsesum,
                           hcb[p1], whh0i, pre_ctxi, pre_xi, c1, hcb[p], h2b[p]);
        // C_s || L1_{s+1}:  L1_{s+1}: A=hcb[p], h2new=h2b[p1]
        hipLaunchKernelGGL(k_cl1, dim3(17 + NL), dim3(256), 0, stream,
                           s, s + 1, 17, h2b[p], fcwbf, fcb, y, lsesum, selbuf, eospbuf,
                           hcb[p], w1i, b1i, c2, h2b[p1]);
    }
    // FC_4 (no lstm blocks)
    hipLaunchKernelGGL(k_fcl0, dim3(NFC), dim3(256), 0, stream,
                       SEG, -1, NFC, h2b[SEG & 1], fcwbf, fcb, lsesum,
                       hcb[0], whh0i, pre_ctxi, pre_xi, c1, hcb[1], h2b[1]);
    // C_4 (no lstm blocks)
    hipLaunchKernelGGL(k_cl1, dim3(17), dim3(256), 0, stream,
                       SEG, -1, 17, h2b[SEG & 1], fcwbf, fcb, y, lsesum, selbuf, eospbuf,
                       hcb[0], w1i, b1i, c2, h2b[1]);

    hipLaunchKernelGGL(k_dp, dim3(1), dim3(256), 0, stream, selbuf, eospbuf, (float*)d_out);
}